// Round 1
// baseline (303.017 us; speedup 1.0000x reference)
//
#include <hip/hip_runtime.h>

#define NW 32
#define BATCH 2048
#define BIGF 1e9f

__global__ __launch_bounds__(64) void floorplan_hungarian_kernel(
    const float* __restrict__ params_true,
    const float* __restrict__ params_pred,
    float* __restrict__ out)
{
    const int b    = blockIdx.x;
    const int lane = threadIdx.x;           // 0..63, one full wave

    __shared__ float cost[NW][NW + 1];      // padded: row reads conflict-free
    __shared__ float featT[NW][9];          // 8 features + pad (stride 9 coprime to 32)
    __shared__ float featP[NW][9];

    // ---------------- Phase 1: per-wall features (1 wall per lane) -------------
    {
        const float* src = (lane < NW)
            ? (params_true + ((size_t)b * NW + lane) * 6)
            : (params_pred + ((size_t)b * NW + (lane - NW)) * 6);
        float sx = src[0], sy = src[1], ex = src[2], ey = src[3];
        float w  = src[4], prob = src[5];

        float dx = ex - sx, dy = ey - sy;
        float cx = (sx + ex) * 0.5f, cy = (sy + ey) * 0.5f;
        float len = sqrtf(dx * dx + dy * dy);
        float area = len * w;

        // side ratio of (width, len)
        float smaller = fminf(w, len), bigger = fmaxf(w, len);
        float sr = (bigger > 0.0f) ? (smaller / bigger) : 0.0f;

        // bounding box (reference _bounding_box)
        float px = dy, py = -dx;
        float pd = len;                      // |per| == |dif|
        if (pd > 0.0f) { px /= pd; py /= pd; }
        px *= w * 0.5f; py *= w * 0.5f;
        float right = fmaxf(fmaxf(sx + px, sx - px), fmaxf(ex + px, ex - px));
        float top   = fmaxf(fmaxf(sy + py, sy - py), fmaxf(ey + py, ey - py));
        float bbw = fabsf((right - cx) * 2.0f);
        float bbh = fabsf((top   - cy) * 2.0f);
        float bba = bbw * bbh;
        float ar  = (bba > 0.001f) ? (area / bba) : 1.0f;

        float* f = (lane < NW) ? featT[lane] : featP[lane - NW];
        f[0] = cx;  f[1] = cy;  f[2] = area; f[3] = sr;
        f[4] = ar;  f[5] = bbw; f[6] = bbh;  f[7] = prob;
    }
    __syncthreads();

    // ---------------- Phase 2: 32x32 cost matrix (16 entries/lane) -------------
    for (int e = lane; e < NW * NW; e += 64) {
        int i = e >> 5, j = e & 31;
        float dcx = featT[i][0] - featP[j][0];
        float dcy = featT[i][1] - featP[j][1];
        float center_d = dcx * dcx + dcy * dcy;
        float da = featT[i][2] - featP[j][2];   float area_d  = da * da;
        float ds = featT[i][3] - featP[j][3];   float lwr_d   = ds * ds;
        float dr = featT[i][4] - featP[j][4];   float rot_d   = dr * dr;
        float dxw = featT[i][5] - featP[j][5];  float horiz_d = dxw * dxw;
        float dyh = featT[i][6] - featP[j][6];  float vert_d  = dyh * dyh;
        float probt = featT[i][7], probp = featP[j][7];
        float dp = probt - probp;               float prob_d  = dp * dp;
        float param_d = area_d + center_d + rot_d + horiz_d + vert_d + lwr_d;
        cost[i][j] = 10.0f * prob_d + param_d * probt;
    }
    __syncthreads();

    // ---------------- Phase 3: Hungarian (JV SAP), one wave per batch ----------
    // lane j (<32) holds column-j state; same lane also holds row-j state.
    float v_col      = 0.0f;   // column potential
    float u_row      = 0.0f;   // row potential (row = lane)
    int   row4col    = -1;     // column -> row
    int   col4row    = -1;     // row -> column

    for (int i0 = 0; i0 < NW; ++i0) {
        bool  SC   = false;
        float spc  = BIGF;
        int   path = -1;
        unsigned srMask = 0;            // uniform bitmask of SR rows
        float minVal = 0.0f;            // uniform
        int i = i0;                     // uniform
        int sink = -1;

        while (sink < 0) {
            srMask |= (1u << i);
            float u_i = __shfl(u_row, i);
            float cij = (lane < NW) ? cost[i][lane] : BIGF;
            float slack = minVal + cij - u_i - v_col;
            if (lane < NW && !SC && slack < spc) { spc = slack; path = i; }

            float mv = (lane >= NW || SC) ? BIGF : spc;
            int   mj = lane;
            #pragma unroll
            for (int off = 32; off >= 1; off >>= 1) {
                float ov = __shfl_xor(mv, off);
                int   oj = __shfl_xor(mj, off);
                if (ov < mv || (ov == mv && oj < mj)) { mv = ov; mj = oj; }
            }
            minVal = mv;                // uniform
            int j = mj;                 // uniform
            if (lane == j) SC = true;
            int r = __shfl(row4col, j); // uniform
            if (r < 0) sink = j; else i = r;
        }

        // potential updates
        {
            int gidx = (col4row < 0) ? 0 : col4row;
            float spc_at_c4r = __shfl(spc, gidx);   // spc[col4row[lane]]
            bool in_SR = (lane < NW) && ((srMask >> lane) & 1u);
            if (lane == i0)                u_row += minVal;
            else if (in_SR)                u_row += minVal - spc_at_c4r;
            if (lane < NW && SC)           v_col -= (minVal - spc);
        }

        // augment along path
        {
            int j = sink;
            while (true) {
                int ii = __shfl(path, j);           // uniform
                if (lane == j) row4col = ii;
                int j_next = __shfl(col4row, ii);   // read before overwrite
                if (lane == ii) col4row = j;
                if (ii == i0) break;
                j = j_next;
            }
        }
    }

    // ---------------- Phase 4: loss = sum of assigned edge costs ---------------
    float myedge = (lane < NW && col4row >= 0) ? cost[lane][col4row] : 0.0f;
    #pragma unroll
    for (int off = 32; off >= 1; off >>= 1)
        myedge += __shfl_xor(myedge, off);
    if (lane == 0) out[b] = myedge;
}

extern "C" void kernel_launch(void* const* d_in, const int* in_sizes, int n_in,
                              void* d_out, int out_size, void* d_ws, size_t ws_size,
                              hipStream_t stream) {
    const float* params_true = (const float*)d_in[0];
    const float* params_pred = (const float*)d_in[1];
    float* out = (float*)d_out;
    floorplan_hungarian_kernel<<<BATCH, 64, 0, stream>>>(params_true, params_pred, out);
}

// Round 3
// 139.217 us; speedup vs baseline: 2.1766x; 2.1766x over previous
//
#include <hip/hip_runtime.h>

#define NW 32
#define BATCH 2048
#define BIGF 1e9f

// One DPP min step: ctrl/row_mask are template params (must be ICEs for the
// builtin). bound_ctrl=false => lanes with invalid source keep old value (x),
// which is the identity for min.
template <int CTRL, int ROW_MASK>
__device__ __forceinline__ float dpp_min_step(float x) {
    int xi = __float_as_int(x);
    int ti = __builtin_amdgcn_update_dpp(xi, xi, CTRL, ROW_MASK, 0xF, false);
    return fminf(x, __int_as_float(ti));
}

// Min across all 64 lanes, returned wave-uniform.
// Canonical GCN pattern: row_shr 1,2,4,8 then row_bcast15 (rows 1,3),
// row_bcast31 (rows 2,3); full reduction lands in lane 63.
__device__ __forceinline__ float wave_min64(float x) {
    x = dpp_min_step<0x111, 0xF>(x); // row_shr:1
    x = dpp_min_step<0x112, 0xF>(x); // row_shr:2
    x = dpp_min_step<0x114, 0xF>(x); // row_shr:4
    x = dpp_min_step<0x118, 0xF>(x); // row_shr:8
    x = dpp_min_step<0x142, 0xA>(x); // row_bcast:15 -> rows 1,3
    x = dpp_min_step<0x143, 0xC>(x); // row_bcast:31 -> rows 2,3
    return __int_as_float(__builtin_amdgcn_readlane(__float_as_int(x), 63));
}

__device__ __forceinline__ float readlane_f(float v, int lane) {
    return __int_as_float(__builtin_amdgcn_readlane(__float_as_int(v), lane));
}

__global__ __launch_bounds__(64) void floorplan_hungarian_kernel(
    const float* __restrict__ params_true,
    const float* __restrict__ params_pred,
    float* __restrict__ out)
{
    const int b    = blockIdx.x;
    const int lane = threadIdx.x;           // 0..63, one full wave

    __shared__ float cost[NW][NW + 1];      // padded rows: conflict-free
    __shared__ float featT[NW][9];
    __shared__ float featP[NW][9];

    // ---------------- Phase 1: per-wall features (1 wall per lane) -------------
    {
        const float* src = (lane < NW)
            ? (params_true + ((size_t)b * NW + lane) * 6)
            : (params_pred + ((size_t)b * NW + (lane - NW)) * 6);
        float sx = src[0], sy = src[1], ex = src[2], ey = src[3];
        float w  = src[4], prob = src[5];

        float dx = ex - sx, dy = ey - sy;
        float cx = (sx + ex) * 0.5f, cy = (sy + ey) * 0.5f;
        float len = sqrtf(dx * dx + dy * dy);
        float area = len * w;

        float smaller = fminf(w, len), bigger = fmaxf(w, len);
        float sr = (bigger > 0.0f) ? (smaller / bigger) : 0.0f;

        float px = dy, py = -dx;
        float pd = len;
        if (pd > 0.0f) { px /= pd; py /= pd; }
        px *= w * 0.5f; py *= w * 0.5f;
        float right = fmaxf(fmaxf(sx + px, sx - px), fmaxf(ex + px, ex - px));
        float top   = fmaxf(fmaxf(sy + py, sy - py), fmaxf(ey + py, ey - py));
        float bbw = fabsf((right - cx) * 2.0f);
        float bbh = fabsf((top   - cy) * 2.0f);
        float bba = bbw * bbh;
        float ar  = (bba > 0.001f) ? (area / bba) : 1.0f;

        float* f = (lane < NW) ? featT[lane] : featP[lane - NW];
        f[0] = cx;  f[1] = cy;  f[2] = area; f[3] = sr;
        f[4] = ar;  f[5] = bbw; f[6] = bbh;  f[7] = prob;
    }
    __syncthreads();

    // ---------------- Phase 2: 32x32 cost matrix (16 entries/lane) -------------
    for (int e = lane; e < NW * NW; e += 64) {
        int i = e >> 5, j = e & 31;
        float dcx = featT[i][0] - featP[j][0];
        float dcy = featT[i][1] - featP[j][1];
        float center_d = dcx * dcx + dcy * dcy;
        float da = featT[i][2] - featP[j][2];   float area_d  = da * da;
        float ds = featT[i][3] - featP[j][3];   float lwr_d   = ds * ds;
        float dr = featT[i][4] - featP[j][4];   float rot_d   = dr * dr;
        float dxw = featT[i][5] - featP[j][5];  float horiz_d = dxw * dxw;
        float dyh = featT[i][6] - featP[j][6];  float vert_d  = dyh * dyh;
        float probt = featT[i][7], probp = featP[j][7];
        float dp = probt - probp;               float prob_d  = dp * dp;
        float param_d = area_d + center_d + rot_d + horiz_d + vert_d + lwr_d;
        cost[i][j] = 10.0f * prob_d + param_d * probt;
    }
    __syncthreads();

    // ---------------- Phase 3: Hungarian (JV SAP), one wave per batch ----------
    // lane j (<32) holds column-j state (v, spc, path, SC, row4col);
    // same lane also holds row-j state (u, col4row).
    const bool isCol = lane < NW;
    float v_col   = 0.0f;
    float u_row   = 0.0f;
    int   row4col = -1;
    int   col4row = -1;

    for (int i0 = 0; i0 < NW; ++i0) {
        bool  SCb   = !isCol;       // lanes >=32: permanently excluded
        float spc   = BIGF;
        int   path  = -1;
        unsigned srMask = 0;        // scalar bitmask of SR rows
        float minVal = 0.0f;        // scalar
        int   i = i0;               // scalar
        int   sink;

        float cij = cost[i][lane & 31];     // prefetched cost row
        while (true) {
            srMask |= (1u << i);
            float u_i   = readlane_f(u_row, i);                  // scalar
            float slack = minVal + cij - u_i - v_col;            // same assoc. as ref
            bool better = (!SCb) && (slack < spc);
            if (better) { spc = slack; path = i; }
            float spcRed = SCb ? BIGF : spc;                     // masked for argmin

            float mv = wave_min64(spcRed);                       // scalar min
            unsigned long long hit = __ballot(spcRed == mv);     // exact-bit match
            int j = __ffsll(hit) - 1;                            // lowest index tie-break
            minVal = mv;
            if (lane == j) SCb = true;
            int r = __builtin_amdgcn_readlane(row4col, j);       // scalar
            if (r < 0) { sink = j; break; }
            i = r;
            cij = cost[i][lane & 31];                            // prefetch next row
        }

        // potential updates
        {
            int gidx = (col4row < 0) ? 0 : col4row;
            float spc_at_c4r = __shfl(spc, gidx);                // per-lane index
            bool in_SR = isCol && ((srMask >> (lane & 31)) & 1u);
            if (lane == i0)              u_row += minVal;
            else if (in_SR)              u_row += minVal - spc_at_c4r;
            if (isCol && SCb)            v_col -= (minVal - spc);
        }

        // augment along path (scalar walk)
        {
            int j = sink;
            while (true) {
                int ii = __builtin_amdgcn_readlane(path, j);
                if (lane == j) row4col = ii;
                int j_next = __builtin_amdgcn_readlane(col4row, ii);
                if (lane == ii) col4row = j;
                if (ii == i0) break;
                j = j_next;
            }
        }
    }

    // ---------------- Phase 4: loss = sum of assigned edge costs ---------------
    float myedge = (isCol && col4row >= 0) ? cost[lane][col4row] : 0.0f;
    #pragma unroll
    for (int off = 32; off >= 1; off >>= 1)
        myedge += __shfl_xor(myedge, off);
    if (lane == 0) out[b] = myedge;
}

extern "C" void kernel_launch(void* const* d_in, const int* in_sizes, int n_in,
                              void* d_out, int out_size, void* d_ws, size_t ws_size,
                              hipStream_t stream) {
    const float* params_true = (const float*)d_in[0];
    const float* params_pred = (const float*)d_in[1];
    float* out = (float*)d_out;
    floorplan_hungarian_kernel<<<BATCH, 64, 0, stream>>>(params_true, params_pred, out);
}